// Round 1
// baseline (1958.448 us; speedup 1.0000x reference)
//
#include <hip/hip_runtime.h>

#define B_   2
#define S_   4096
#define H_   16
#define DK_  128
#define DV_  128
#define CK_  64
#define NC_  (S_/CK_)            // 64 chunks per sequence
#define QSCALE 0.08838834764831845f   // 128^-0.5

// ---------------- Phase 1: per-chunk (parallel over 2048 chunks) ----------------
// Computes per chunk: gcs (cumsum g), Tinv = (I + strict_lower(k_beta k^T * decay))^-1,
// u = Tinv @ (v*beta), kcd = Tinv @ (k*beta*exp(gcs)), attn = tril(q k^T * decay).
__global__ __launch_bounds__(256) void dr_phase1(
    const float* __restrict__ Q, const float* __restrict__ K,
    const float* __restrict__ V, const float* __restrict__ G,
    const float* __restrict__ Bt,
    float* __restrict__ Uw, float* __restrict__ KCDw,
    float* __restrict__ ATTNw, float* __restrict__ GCSw)
{
    __shared__ float kn[64][129];    // normalized k
    __shared__ float buf[64][129];   // v*beta, later q normalized+scaled
    __shared__ float T[64][65];      // -(A), becomes strict-lower part of Tinv
    __shared__ float pt[64][5];
    __shared__ float gcs[64], bet[64], w_s[64], rn[64], epos[64], eneg[64];

    const int tid = threadIdx.x;
    const int cid = blockIdx.x;
    const int n   = cid & (NC_ - 1);
    const int bh  = cid >> 6;
    const int h   = bh & (H_ - 1);
    const int b   = bh >> 4;
    const int rowbase = (b*S_ + n*CK_)*H_ + h;   // row index in [B*S*H]

    // load k chunk, g, beta
    for (int idx = tid; idx < 64*128; idx += 256) {
        int r = idx >> 7, c = idx & 127;
        kn[r][c] = K[(rowbase + r*H_)*DK_ + c];
    }
    if (tid < 64) {
        gcs[tid] = G[rowbase + tid*H_];
        bet[tid] = Bt[rowbase + tid*H_];
    }
    __syncthreads();

    // cumsum(g) by t0; k row norms by wave 1
    if (tid == 0) {
        float a = 0.f;
        for (int r = 0; r < 64; ++r) { a += gcs[r]; gcs[r] = a; }
    }
    if (tid >= 64 && tid < 128) {
        int r = tid - 64;
        float s = 0.f;
        for (int c = 0; c < 128; ++c) { float x = kn[r][c]; s += x*x; }
        rn[r] = rsqrtf(s + 1e-6f);
    }
    __syncthreads();

    if (tid < 64) {
        float gv = gcs[tid];
        float ep = expf(gv);
        epos[tid] = ep;
        eneg[tid] = expf(-gv);
        w_s[tid]  = bet[tid]*ep;     // beta * exp(gcs)
    }
    for (int idx = tid; idx < 64*128; idx += 256) {
        int r = idx >> 7, c = idx & 127;
        kn[r][c] *= rn[r];
        buf[r][c] = V[(rowbase + r*H_)*DV_ + c]*bet[r];
    }
    __syncthreads();

    // T = -strict_lower( (k*beta) @ k^T * decay ), 4x4 register tiles
    {
        const int i0 = (tid >> 4) << 2, j0 = (tid & 15) << 2;
        float acc[4][4] = {};
        if (j0 <= i0) {
            for (int c = 0; c < 128; ++c) {
                float a0=kn[i0][c],a1=kn[i0+1][c],a2=kn[i0+2][c],a3=kn[i0+3][c];
                float b0=kn[j0][c],b1=kn[j0+1][c],b2=kn[j0+2][c],b3=kn[j0+3][c];
                acc[0][0]+=a0*b0; acc[0][1]+=a0*b1; acc[0][2]+=a0*b2; acc[0][3]+=a0*b3;
                acc[1][0]+=a1*b0; acc[1][1]+=a1*b1; acc[1][2]+=a1*b2; acc[1][3]+=a1*b3;
                acc[2][0]+=a2*b0; acc[2][1]+=a2*b1; acc[2][2]+=a2*b2; acc[2][3]+=a2*b3;
                acc[3][0]+=a3*b0; acc[3][1]+=a3*b1; acc[3][2]+=a3*b2; acc[3][3]+=a3*b3;
            }
        }
        #pragma unroll
        for (int x = 0; x < 4; ++x)
            #pragma unroll
            for (int y = 0; y < 4; ++y) {
                int i = i0+x, j = j0+y;
                T[i][j] = (i > j) ? (-bet[i]*epos[i]*eneg[j]*acc[x][y]) : 0.f;
            }
    }
    __syncthreads();

    // in-place unit-lower inverse: row i gets  T[i,:i] += T[i,:i] @ T[:i,:i]
    // (4 partial sums per column j, then reduce)
    for (int i = 1; i < 64; ++i) {
        const int j = tid & 63, p = tid >> 6;
        float s = 0.f;
        if (j < i)
            for (int l = j+1+p; l < i; l += 4) s += T[i][l]*T[l][j];
        pt[j][p] = s;
        __syncthreads();
        if (tid < i) T[i][tid] += pt[tid][0]+pt[tid][1]+pt[tid][2]+pt[tid][3];
        __syncthreads();
    }

    // U = (I+T) @ (v*beta)    and    KCD = (I+T) @ (k * beta * exp(gcs))
    {
        float* Up = Uw + cid*(CK_*DV_);
        for (int tt = tid; tt < 512; tt += 256) {
            const int i0 = (tt >> 5) << 2, c0 = (tt & 31) << 2;
            float acc[4][4];
            #pragma unroll
            for (int x = 0; x < 4; ++x)
                #pragma unroll
                for (int y = 0; y < 4; ++y) acc[x][y] = buf[i0+x][c0+y];
            for (int j = 0; j < i0+4; ++j) {   // T has zeros on/above diag
                float t0=T[i0][j],t1=T[i0+1][j],t2=T[i0+2][j],t3=T[i0+3][j];
                float b0=buf[j][c0],b1=buf[j][c0+1],b2=buf[j][c0+2],b3=buf[j][c0+3];
                acc[0][0]+=t0*b0; acc[0][1]+=t0*b1; acc[0][2]+=t0*b2; acc[0][3]+=t0*b3;
                acc[1][0]+=t1*b0; acc[1][1]+=t1*b1; acc[1][2]+=t1*b2; acc[1][3]+=t1*b3;
                acc[2][0]+=t2*b0; acc[2][1]+=t2*b1; acc[2][2]+=t2*b2; acc[2][3]+=t2*b3;
                acc[3][0]+=t3*b0; acc[3][1]+=t3*b1; acc[3][2]+=t3*b2; acc[3][3]+=t3*b3;
            }
            #pragma unroll
            for (int x = 0; x < 4; ++x)
                #pragma unroll
                for (int y = 0; y < 4; ++y) Up[(i0+x)*DV_ + c0+y] = acc[x][y];
        }
        float* Kp = KCDw + cid*(CK_*DK_);
        for (int tt = tid; tt < 512; tt += 256) {
            const int i0 = (tt >> 5) << 2, c0 = (tt & 31) << 2;
            float acc[4][4];
            #pragma unroll
            for (int x = 0; x < 4; ++x) {
                float wi = w_s[i0+x];
                #pragma unroll
                for (int y = 0; y < 4; ++y) acc[x][y] = kn[i0+x][c0+y]*wi;
            }
            for (int j = 0; j < i0+4; ++j) {
                float wj = w_s[j];
                float t0=T[i0][j],t1=T[i0+1][j],t2=T[i0+2][j],t3=T[i0+3][j];
                float b0=kn[j][c0]*wj,b1=kn[j][c0+1]*wj,b2=kn[j][c0+2]*wj,b3=kn[j][c0+3]*wj;
                acc[0][0]+=t0*b0; acc[0][1]+=t0*b1; acc[0][2]+=t0*b2; acc[0][3]+=t0*b3;
                acc[1][0]+=t1*b0; acc[1][1]+=t1*b1; acc[1][2]+=t1*b2; acc[1][3]+=t1*b3;
                acc[2][0]+=t2*b0; acc[2][1]+=t2*b1; acc[2][2]+=t2*b2; acc[2][3]+=t2*b3;
                acc[3][0]+=t3*b0; acc[3][1]+=t3*b1; acc[3][2]+=t3*b2; acc[3][3]+=t3*b3;
            }
            #pragma unroll
            for (int x = 0; x < 4; ++x)
                #pragma unroll
                for (int y = 0; y < 4; ++y) Kp[(i0+x)*DK_ + c0+y] = acc[x][y];
        }
    }
    __syncthreads();

    // load q into buf, normalize, scale
    for (int idx = tid; idx < 64*128; idx += 256) {
        int r = idx >> 7, c = idx & 127;
        buf[r][c] = Q[(rowbase + r*H_)*DK_ + c];
    }
    __syncthreads();
    if (tid < 64) {
        float s = 0.f;
        for (int c = 0; c < 128; ++c) { float x = buf[tid][c]; s += x*x; }
        rn[tid] = rsqrtf(s + 1e-6f)*QSCALE;
    }
    __syncthreads();
    for (int idx = tid; idx < 64*128; idx += 256) {
        int r = idx >> 7, c = idx & 127;
        buf[r][c] *= rn[r];
    }
    __syncthreads();

    // attn = tril incl diag of (q_norm @ k_norm^T * decay)
    {
        float* Ap = ATTNw + cid*(CK_*CK_);
        const int i0 = (tid >> 4) << 2, j0 = (tid & 15) << 2;
        float acc[4][4] = {};
        if (j0 <= i0) {
            for (int c = 0; c < 128; ++c) {
                float a0=buf[i0][c],a1=buf[i0+1][c],a2=buf[i0+2][c],a3=buf[i0+3][c];
                float b0=kn[j0][c],b1=kn[j0+1][c],b2=kn[j0+2][c],b3=kn[j0+3][c];
                acc[0][0]+=a0*b0; acc[0][1]+=a0*b1; acc[0][2]+=a0*b2; acc[0][3]+=a0*b3;
                acc[1][0]+=a1*b0; acc[1][1]+=a1*b1; acc[1][2]+=a1*b2; acc[1][3]+=a1*b3;
                acc[2][0]+=a2*b0; acc[2][1]+=a2*b1; acc[2][2]+=a2*b2; acc[2][3]+=a2*b3;
                acc[3][0]+=a3*b0; acc[3][1]+=a3*b1; acc[3][2]+=a3*b2; acc[3][3]+=a3*b3;
            }
        }
        #pragma unroll
        for (int x = 0; x < 4; ++x)
            #pragma unroll
            for (int y = 0; y < 4; ++y) {
                int i = i0+x, j = j0+y;
                Ap[i*CK_ + j] = (j <= i) ? acc[x][y]*epos[i]*eneg[j] : 0.f;
            }
    }
    if (tid < 64) GCSw[cid*CK_ + tid] = gcs[tid];
}

// ---------------- Phase 2: sequential chunk scan, Dv-sliced (256 blocks) ----------------
__global__ __launch_bounds__(256) void dr_phase2(
    const float* __restrict__ Q, const float* __restrict__ K,
    const float* __restrict__ Uw, const float* __restrict__ KCDw,
    const float* __restrict__ ATTNw, const float* __restrict__ GCSw,
    float* __restrict__ Out)
{
    __shared__ float qg[64][129];     // q_norm * scale * exp(gcs)
    __shared__ float kd[64][129];     // k_norm * exp(g_last - gcs)
    __shared__ float kc[64][129];     // kcd chunk
    __shared__ float at[64][65];      // attn chunk (masked, zeros above diag)
    __shared__ float st[128][17];     // state slice [Dk][16]
    __shared__ float vn[64][17];      // v_new slice
    __shared__ float gcs[64], rq[64], rk[64];

    const int tid = threadIdx.x;
    const int vs  = blockIdx.x & 7;        // 8 slices of 16 v-columns
    const int bh  = blockIdx.x >> 3;
    const int h   = bh & (H_ - 1);
    const int b   = bh >> 4;
    const int v0  = vs*16;

    for (int idx = tid; idx < 128*17; idx += 256) (&st[0][0])[idx] = 0.f;

    const int rp = tid >> 3, vp = tid & 7;
    const int r0 = rp*2,  w0 = vp*2;

    for (int n = 0; n < NC_; ++n) {
        const int cid = bh*NC_ + n;
        const int rowbase = (b*S_ + n*CK_)*H_ + h;

        if (tid < 64) gcs[tid] = GCSw[cid*CK_ + tid];
        for (int idx = tid; idx < 64*128; idx += 256) {
            int r = idx >> 7, c = idx & 127;
            qg[r][c] = Q[(rowbase + r*H_)*DK_ + c];
            kd[r][c] = K[(rowbase + r*H_)*DK_ + c];
            kc[r][c] = KCDw[cid*(CK_*DK_) + idx];
        }
        for (int idx = tid; idx < 4096; idx += 256)
            at[idx >> 6][idx & 63] = ATTNw[cid*(CK_*CK_) + idx];
        __syncthreads();

        if (tid < 64) {
            float sq = 0.f, sk = 0.f;
            for (int c = 0; c < 128; ++c) {
                float xq = qg[tid][c]; sq += xq*xq;
                float xk = kd[tid][c]; sk += xk*xk;
            }
            float gl = gcs[63];
            rq[tid] = rsqrtf(sq + 1e-6f)*QSCALE*expf(gcs[tid]);
            rk[tid] = rsqrtf(sk + 1e-6f)*expf(gl - gcs[tid]);
        }
        __syncthreads();
        for (int idx = tid; idx < 64*128; idx += 256) {
            int r = idx >> 7, c = idx & 127;
            qg[r][c] *= rq[r];
            kd[r][c] *= rk[r];
        }
        __syncthreads();

        // v_new = u - kcd @ state     (2x2 register tile per thread)
        {
            const float* Uc = Uw + cid*(CK_*DV_);
            float s00 = Uc[r0*DV_ + v0+w0],     s01 = Uc[r0*DV_ + v0+w0+1];
            float s10 = Uc[(r0+1)*DV_ + v0+w0], s11 = Uc[(r0+1)*DV_ + v0+w0+1];
            for (int kk = 0; kk < 128; ++kk) {
                float a0 = kc[r0][kk], a1 = kc[r0+1][kk];
                float b0 = st[kk][w0], b1 = st[kk][w0+1];
                s00 -= a0*b0; s01 -= a0*b1; s10 -= a1*b0; s11 -= a1*b1;
            }
            vn[r0][w0] = s00; vn[r0][w0+1] = s01;
            vn[r0+1][w0] = s10; vn[r0+1][w0+1] = s11;
        }
        __syncthreads();

        // o = qg @ state + attn @ v_new
        {
            float s00 = 0.f, s01 = 0.f, s10 = 0.f, s11 = 0.f;
            for (int kk = 0; kk < 128; ++kk) {
                float a0 = qg[r0][kk], a1 = qg[r0+1][kk];
                float b0 = st[kk][w0], b1 = st[kk][w0+1];
                s00 += a0*b0; s01 += a0*b1; s10 += a1*b0; s11 += a1*b1;
            }
            for (int j = 0; j <= r0+1; ++j) {   // at[] holds zeros above diagonal
                float a0 = at[r0][j], a1 = at[r0+1][j];
                float b0 = vn[j][w0], b1 = vn[j][w0+1];
                s00 += a0*b0; s01 += a0*b1; s10 += a1*b0; s11 += a1*b1;
            }
            int o0 = (rowbase + r0*H_)*DV_ + v0 + w0;
            int o1 = (rowbase + (r0+1)*H_)*DV_ + v0 + w0;
            Out[o0] = s00; Out[o0+1] = s01;
            Out[o1] = s10; Out[o1+1] = s11;
        }
        __syncthreads();

        // state = exp(g_last)*state + kd^T @ v_new   (4x2 tile per thread)
        {
            const float eg = expf(gcs[63]);
            const int k0 = (tid >> 3)*4;
            float s0 = st[k0][w0]*eg,   t0 = st[k0][w0+1]*eg;
            float s1 = st[k0+1][w0]*eg, t1 = st[k0+1][w0+1]*eg;
            float s2 = st[k0+2][w0]*eg, t2 = st[k0+2][w0+1]*eg;
            float s3 = st[k0+3][w0]*eg, t3 = st[k0+3][w0+1]*eg;
            for (int r = 0; r < 64; ++r) {
                float b0 = vn[r][w0], b1 = vn[r][w0+1];
                float a0 = kd[r][k0], a1 = kd[r][k0+1], a2 = kd[r][k0+2], a3 = kd[r][k0+3];
                s0 += a0*b0; t0 += a0*b1;
                s1 += a1*b0; t1 += a1*b1;
                s2 += a2*b0; t2 += a2*b1;
                s3 += a3*b0; t3 += a3*b1;
            }
            st[k0][w0] = s0;   st[k0][w0+1] = t0;
            st[k0+1][w0] = s1; st[k0+1][w0+1] = t1;
            st[k0+2][w0] = s2; st[k0+2][w0+1] = t2;
            st[k0+3][w0] = s3; st[k0+3][w0+1] = t3;
        }
        __syncthreads();
    }
}

extern "C" void kernel_launch(void* const* d_in, const int* in_sizes, int n_in,
                              void* d_out, int out_size, void* d_ws, size_t ws_size,
                              hipStream_t stream) {
    (void)in_sizes; (void)n_in; (void)out_size; (void)ws_size;
    const float* Q  = (const float*)d_in[0];
    const float* K  = (const float*)d_in[1];
    const float* V  = (const float*)d_in[2];
    const float* G  = (const float*)d_in[3];
    const float* Bt = (const float*)d_in[4];
    float* Out = (float*)d_out;

    // ws layout (fp32): U[2048][64][128] | KCD[2048][64][128] | ATTN[2048][64][64] | GCS[2048][64]
    // total = 42,074,112 floats = 168.3 MB
    float* Uw   = (float*)d_ws;
    float* KCDw = Uw   + 2048*64*128;
    float* ATTNw= KCDw + 2048*64*128;
    float* GCSw = ATTNw+ 2048*64*64;

    dr_phase1<<<2048, 256, 0, stream>>>(Q, K, V, G, Bt, Uw, KCDw, ATTNw, GCSw);
    dr_phase2<<<256, 256, 0, stream>>>(Q, K, Uw, KCDw, ATTNw, GCSw, Out);
}

// Round 2
// 1222.457 us; speedup vs baseline: 1.6021x; 1.6021x over previous
//
#include <hip/hip_runtime.h>

#define B_   2
#define S_   4096
#define H_   16
#define DK_  128
#define DV_  128
#define CK_  64
#define NC_  (S_/CK_)            // 64 chunks per sequence
#define QSCALE 0.08838834764831845f   // 128^-0.5

#define DOT4(a,b) ((a).x*(b).x + (a).y*(b).y + (a).z*(b).z + (a).w*(b).w)

static __device__ __forceinline__ unsigned short f2bf(float x) {
    unsigned u = __float_as_uint(x);
    unsigned r = u + 0x7fffu + ((u >> 16) & 1u);
    return (unsigned short)(r >> 16);
}
static __device__ __forceinline__ float bf2f(unsigned short h) {
    return __uint_as_float(((unsigned)h) << 16);
}

// ---------------- Phase 1: per-chunk (parallel over 2048 chunks) ----------------
// Outputs (bf16): U = Tinv@(v*beta), KCD = Tinv@(k*beta*exp(gcs)), ATTN = tril(qk^T*decay)
// Outputs (fp32): RQ' = rsqrt_q*QSCALE*exp(gcs), RK' = rsqrt_k*exp(g_last-gcs), EG = exp(g_last)
__global__ __launch_bounds__(256) void dr_phase1(
    const float* __restrict__ Q, const float* __restrict__ K,
    const float* __restrict__ V, const float* __restrict__ G,
    const float* __restrict__ Bt,
    unsigned short* __restrict__ Uw, unsigned short* __restrict__ KCDw,
    unsigned short* __restrict__ ATTNw,
    float* __restrict__ RQw, float* __restrict__ RKw, float* __restrict__ EGw)
{
    __shared__ float kn[64][132];
    __shared__ float buf[64][132];
    __shared__ float T[64][68];
    __shared__ float pt[64][5];
    __shared__ float gcs[64], bet[64], w_s[64], rn[64], epos[64], eneg[64];

    const int tid = threadIdx.x;
    const int cid = blockIdx.x;
    const int n   = cid & (NC_ - 1);
    const int bh  = cid >> 6;
    const int h   = bh & (H_ - 1);
    const int b   = bh >> 4;
    const int rowbase = (b*S_ + n*CK_)*H_ + h;

    // load k chunk (float4), g, beta
    #pragma unroll
    for (int i = 0; i < 8; ++i) {
        int idx4 = tid + 256*i;
        int r = idx4 >> 5, c0 = (idx4 & 31) << 2;
        *(float4*)&kn[r][c0] = *(const float4*)(K + (size_t)(rowbase + r*H_)*DK_ + c0);
    }
    if (tid < 64) {
        gcs[tid] = G[rowbase + tid*H_];
        bet[tid] = Bt[rowbase + tid*H_];
    }
    __syncthreads();

    if (tid == 0) {
        float a = 0.f;
        for (int r = 0; r < 64; ++r) { a += gcs[r]; gcs[r] = a; }
    }
    if (tid >= 64 && tid < 128) {
        int r = tid - 64;
        float s = 0.f;
        for (int c = 0; c < 128; c += 4) { float4 x = *(float4*)&kn[r][c]; s += DOT4(x,x); }
        rn[r] = rsqrtf(s + 1e-6f);
    }
    __syncthreads();

    if (tid < 64) {
        float gv = gcs[tid];
        float ep = expf(gv);
        epos[tid] = ep;
        eneg[tid] = expf(-gv);
        w_s[tid]  = bet[tid]*ep;
    }
    __syncthreads();

    if (tid < 64) RKw[cid*64 + tid] = rn[tid]*epos[63]*eneg[tid];
    if (tid == 0) EGw[cid] = epos[63];
    #pragma unroll
    for (int i = 0; i < 8; ++i) {
        int idx4 = tid + 256*i;
        int r = idx4 >> 5, c0 = (idx4 & 31) << 2;
        float rr = rn[r];
        float4 kv = *(float4*)&kn[r][c0];
        kv.x *= rr; kv.y *= rr; kv.z *= rr; kv.w *= rr;
        *(float4*)&kn[r][c0] = kv;
        float bb = bet[r];
        float4 vv = *(const float4*)(V + (size_t)(rowbase + r*H_)*DV_ + c0);
        vv.x *= bb; vv.y *= bb; vv.z *= bb; vv.w *= bb;
        *(float4*)&buf[r][c0] = vv;
    }
    __syncthreads();

    // T = -strict_lower( (k*beta) @ k^T * decay )
    {
        const int i0 = (tid >> 4) << 2, j0 = (tid & 15) << 2;
        float acc[4][4] = {};
        if (j0 <= i0) {
            for (int c = 0; c < 128; c += 4) {
                float4 a0 = *(float4*)&kn[i0][c],   a1 = *(float4*)&kn[i0+1][c];
                float4 a2 = *(float4*)&kn[i0+2][c], a3 = *(float4*)&kn[i0+3][c];
                float4 b0 = *(float4*)&kn[j0][c],   b1 = *(float4*)&kn[j0+1][c];
                float4 b2 = *(float4*)&kn[j0+2][c], b3 = *(float4*)&kn[j0+3][c];
                acc[0][0]+=DOT4(a0,b0); acc[0][1]+=DOT4(a0,b1); acc[0][2]+=DOT4(a0,b2); acc[0][3]+=DOT4(a0,b3);
                acc[1][0]+=DOT4(a1,b0); acc[1][1]+=DOT4(a1,b1); acc[1][2]+=DOT4(a1,b2); acc[1][3]+=DOT4(a1,b3);
                acc[2][0]+=DOT4(a2,b0); acc[2][1]+=DOT4(a2,b1); acc[2][2]+=DOT4(a2,b2); acc[2][3]+=DOT4(a2,b3);
                acc[3][0]+=DOT4(a3,b0); acc[3][1]+=DOT4(a3,b1); acc[3][2]+=DOT4(a3,b2); acc[3][3]+=DOT4(a3,b3);
            }
        }
        #pragma unroll
        for (int x = 0; x < 4; ++x)
            #pragma unroll
            for (int y = 0; y < 4; ++y) {
                int i = i0+x, j = j0+y;
                T[i][j] = (i > j) ? (-bet[i]*epos[i]*eneg[j]*acc[x][y]) : 0.f;
            }
    }
    __syncthreads();

    // in-place unit-lower inverse
    for (int i = 1; i < 64; ++i) {
        const int j = tid & 63, p = tid >> 6;
        float s = 0.f;
        if (j < i)
            for (int l = j+1+p; l < i; l += 4) s += T[i][l]*T[l][j];
        pt[j][p] = s;
        __syncthreads();
        if (tid < i) T[i][tid] += pt[tid][0]+pt[tid][1]+pt[tid][2]+pt[tid][3];
        __syncthreads();
    }

    // U = (I+T) @ (v*beta),  KCD = (I+T) @ (k*beta*exp(gcs))  -> bf16
    {
        unsigned short* Up = Uw + (size_t)cid*(CK_*DV_);
        for (int tt = tid; tt < 512; tt += 256) {
            const int i0 = (tt >> 5) << 2, c0 = (tt & 31) << 2;
            float4 acc[4];
            #pragma unroll
            for (int x = 0; x < 4; ++x) acc[x] = *(float4*)&buf[i0+x][c0];
            for (int j0 = 0; j0 <= i0; j0 += 4) {
                float4 t0 = *(float4*)&T[i0][j0],   t1 = *(float4*)&T[i0+1][j0];
                float4 t2 = *(float4*)&T[i0+2][j0], t3 = *(float4*)&T[i0+3][j0];
                float4 b0 = *(float4*)&buf[j0][c0],   b1 = *(float4*)&buf[j0+1][c0];
                float4 b2 = *(float4*)&buf[j0+2][c0], b3 = *(float4*)&buf[j0+3][c0];
                acc[0].x += t0.x*b0.x + t0.y*b1.x + t0.z*b2.x + t0.w*b3.x;
                acc[0].y += t0.x*b0.y + t0.y*b1.y + t0.z*b2.y + t0.w*b3.y;
                acc[0].z += t0.x*b0.z + t0.y*b1.z + t0.z*b2.z + t0.w*b3.z;
                acc[0].w += t0.x*b0.w + t0.y*b1.w + t0.z*b2.w + t0.w*b3.w;
                acc[1].x += t1.x*b0.x + t1.y*b1.x + t1.z*b2.x + t1.w*b3.x;
                acc[1].y += t1.x*b0.y + t1.y*b1.y + t1.z*b2.y + t1.w*b3.y;
                acc[1].z += t1.x*b0.z + t1.y*b1.z + t1.z*b2.z + t1.w*b3.z;
                acc[1].w += t1.x*b0.w + t1.y*b1.w + t1.z*b2.w + t1.w*b3.w;
                acc[2].x += t2.x*b0.x + t2.y*b1.x + t2.z*b2.x + t2.w*b3.x;
                acc[2].y += t2.x*b0.y + t2.y*b1.y + t2.z*b2.y + t2.w*b3.y;
                acc[2].z += t2.x*b0.z + t2.y*b1.z + t2.z*b2.z + t2.w*b3.z;
                acc[2].w += t2.x*b0.w + t2.y*b1.w + t2.z*b2.w + t2.w*b3.w;
                acc[3].x += t3.x*b0.x + t3.y*b1.x + t3.z*b2.x + t3.w*b3.x;
                acc[3].y += t3.x*b0.y + t3.y*b1.y + t3.z*b2.y + t3.w*b3.y;
                acc[3].z += t3.x*b0.z + t3.y*b1.z + t3.z*b2.z + t3.w*b3.z;
                acc[3].w += t3.x*b0.w + t3.y*b1.w + t3.z*b2.w + t3.w*b3.w;
            }
            #pragma unroll
            for (int x = 0; x < 4; ++x) {
                ushort4 o; o.x = f2bf(acc[x].x); o.y = f2bf(acc[x].y);
                o.z = f2bf(acc[x].z); o.w = f2bf(acc[x].w);
                *(ushort4*)(Up + (i0+x)*DV_ + c0) = o;
            }
        }
        unsigned short* Kp = KCDw + (size_t)cid*(CK_*DK_);
        for (int tt = tid; tt < 512; tt += 256) {
            const int i0 = (tt >> 5) << 2, c0 = (tt & 31) << 2;
            float4 acc[4];
            #pragma unroll
            for (int x = 0; x < 4; ++x) {
                float wi = w_s[i0+x];
                float4 kv = *(float4*)&kn[i0+x][c0];
                acc[x].x = kv.x*wi; acc[x].y = kv.y*wi; acc[x].z = kv.z*wi; acc[x].w = kv.w*wi;
            }
            for (int j0 = 0; j0 <= i0; j0 += 4) {
                float w0 = w_s[j0], w1 = w_s[j0+1], w2 = w_s[j0+2], w3 = w_s[j0+3];
                float4 t0 = *(float4*)&T[i0][j0],   t1 = *(float4*)&T[i0+1][j0];
                float4 t2 = *(float4*)&T[i0+2][j0], t3 = *(float4*)&T[i0+3][j0];
                float4 b0 = *(float4*)&kn[j0][c0],   b1 = *(float4*)&kn[j0+1][c0];
                float4 b2 = *(float4*)&kn[j0+2][c0], b3 = *(float4*)&kn[j0+3][c0];
                b0.x*=w0; b0.y*=w0; b0.z*=w0; b0.w*=w0;
                b1.x*=w1; b1.y*=w1; b1.z*=w1; b1.w*=w1;
                b2.x*=w2; b2.y*=w2; b2.z*=w2; b2.w*=w2;
                b3.x*=w3; b3.y*=w3; b3.z*=w3; b3.w*=w3;
                acc[0].x += t0.x*b0.x + t0.y*b1.x + t0.z*b2.x + t0.w*b3.x;
                acc[0].y += t0.x*b0.y + t0.y*b1.y + t0.z*b2.y + t0.w*b3.y;
                acc[0].z += t0.x*b0.z + t0.y*b1.z + t0.z*b2.z + t0.w*b3.z;
                acc[0].w += t0.x*b0.w + t0.y*b1.w + t0.z*b2.w + t0.w*b3.w;
                acc[1].x += t1.x*b0.x + t1.y*b1.x + t1.z*b2.x + t1.w*b3.x;
                acc[1].y += t1.x*b0.y + t1.y*b1.y + t1.z*b2.y + t1.w*b3.y;
                acc[1].z += t1.x*b0.z + t1.y*b1.z + t1.z*b2.z + t1.w*b3.z;
                acc[1].w += t1.x*b0.w + t1.y*b1.w + t1.z*b2.w + t1.w*b3.w;
                acc[2].x += t2.x*b0.x + t2.y*b1.x + t2.z*b2.x + t2.w*b3.x;
                acc[2].y += t2.x*b0.y + t2.y*b1.y + t2.z*b2.y + t2.w*b3.y;
                acc[2].z += t2.x*b0.z + t2.y*b1.z + t2.z*b2.z + t2.w*b3.z;
                acc[2].w += t2.x*b0.w + t2.y*b1.w + t2.z*b2.w + t2.w*b3.w;
                acc[3].x += t3.x*b0.x + t3.y*b1.x + t3.z*b2.x + t3.w*b3.x;
                acc[3].y += t3.x*b0.y + t3.y*b1.y + t3.z*b2.y + t3.w*b3.y;
                acc[3].z += t3.x*b0.z + t3.y*b1.z + t3.z*b2.z + t3.w*b3.z;
                acc[3].w += t3.x*b0.w + t3.y*b1.w + t3.z*b2.w + t3.w*b3.w;
            }
            #pragma unroll
            for (int x = 0; x < 4; ++x) {
                ushort4 o; o.x = f2bf(acc[x].x); o.y = f2bf(acc[x].y);
                o.z = f2bf(acc[x].z); o.w = f2bf(acc[x].w);
                *(ushort4*)(Kp + (i0+x)*DK_ + c0) = o;
            }
        }
    }
    __syncthreads();

    // q into buf, normalize (with QSCALE)
    #pragma unroll
    for (int i = 0; i < 8; ++i) {
        int idx4 = tid + 256*i;
        int r = idx4 >> 5, c0 = (idx4 & 31) << 2;
        *(float4*)&buf[r][c0] = *(const float4*)(Q + (size_t)(rowbase + r*H_)*DK_ + c0);
    }
    __syncthreads();
    if (tid < 64) {
        float s = 0.f;
        for (int c = 0; c < 128; c += 4) { float4 x = *(float4*)&buf[tid][c]; s += DOT4(x,x); }
        rn[tid] = rsqrtf(s + 1e-6f)*QSCALE;
        RQw[cid*64 + tid] = rn[tid]*epos[tid];
    }
    __syncthreads();
    #pragma unroll
    for (int i = 0; i < 8; ++i) {
        int idx4 = tid + 256*i;
        int r = idx4 >> 5, c0 = (idx4 & 31) << 2;
        float rr = rn[r];
        float4 qv = *(float4*)&buf[r][c0];
        qv.x *= rr; qv.y *= rr; qv.z *= rr; qv.w *= rr;
        *(float4*)&buf[r][c0] = qv;
    }
    __syncthreads();

    // attn = tril(q@k^T * decay) -> bf16
    {
        unsigned short* Ap = ATTNw + (size_t)cid*(CK_*CK_);
        const int i0 = (tid >> 4) << 2, j0 = (tid & 15) << 2;
        float acc[4][4] = {};
        if (j0 <= i0) {
            for (int c = 0; c < 128; c += 4) {
                float4 a0 = *(float4*)&buf[i0][c],   a1 = *(float4*)&buf[i0+1][c];
                float4 a2 = *(float4*)&buf[i0+2][c], a3 = *(float4*)&buf[i0+3][c];
                float4 b0 = *(float4*)&kn[j0][c],   b1 = *(float4*)&kn[j0+1][c];
                float4 b2 = *(float4*)&kn[j0+2][c], b3 = *(float4*)&kn[j0+3][c];
                acc[0][0]+=DOT4(a0,b0); acc[0][1]+=DOT4(a0,b1); acc[0][2]+=DOT4(a0,b2); acc[0][3]+=DOT4(a0,b3);
                acc[1][0]+=DOT4(a1,b0); acc[1][1]+=DOT4(a1,b1); acc[1][2]+=DOT4(a1,b2); acc[1][3]+=DOT4(a1,b3);
                acc[2][0]+=DOT4(a2,b0); acc[2][1]+=DOT4(a2,b1); acc[2][2]+=DOT4(a2,b2); acc[2][3]+=DOT4(a2,b3);
                acc[3][0]+=DOT4(a3,b0); acc[3][1]+=DOT4(a3,b1); acc[3][2]+=DOT4(a3,b2); acc[3][3]+=DOT4(a3,b3);
            }
        }
        #pragma unroll
        for (int x = 0; x < 4; ++x) {
            ushort4 o;
            int i = i0+x;
            float v0 = (j0   <= i) ? acc[x][0]*epos[i]*eneg[j0]   : 0.f;
            float v1 = (j0+1 <= i) ? acc[x][1]*epos[i]*eneg[j0+1] : 0.f;
            float v2 = (j0+2 <= i) ? acc[x][2]*epos[i]*eneg[j0+2] : 0.f;
            float v3 = (j0+3 <= i) ? acc[x][3]*epos[i]*eneg[j0+3] : 0.f;
            o.x = f2bf(v0); o.y = f2bf(v1); o.z = f2bf(v2); o.w = f2bf(v3);
            *(ushort4*)(Ap + i*CK_ + j0) = o;
        }
    }
}

// ---------------- Phase 2: state recurrence only (256 blocks = bh x 8 v-slices) ----------------
__global__ __launch_bounds__(256) void dr_phase2(
    const float* __restrict__ K,
    const unsigned short* __restrict__ Uw, const unsigned short* __restrict__ KCDw,
    const float* __restrict__ RKw, const float* __restrict__ EGw,
    unsigned short* __restrict__ STw)
{
    __shared__ float kc[64][132];    // kcd fp32
    __shared__ float kd[64][132];    // k_norm * exp(g_last - gcs)
    __shared__ float stT[16][132];   // state^T slice: stT[v][k]
    __shared__ float vn[64][20];     // v_new slice

    const int tid = threadIdx.x;
    const int vs = blockIdx.x & 7, bh = blockIdx.x >> 3;
    const int h = bh & (H_-1), b = bh >> 4;
    const int v0 = vs*16;

    for (int i = tid; i < 16*132; i += 256) (&stT[0][0])[i] = 0.f;
    __syncthreads();

    const int rg = tid >> 3, wg = tid & 7;
    const int r0 = rg*2, w0v = wg*2;            // vn tile
    const int wq = tid >> 5, kq = tid & 31;
    const int w0s = wq*2, k0s = kq*4;           // state tile
    const int srow = tid >> 4, scol = (tid & 15)*8;   // ST store map

    for (int n = 0; n < NC_; ++n) {
        const int cid = bh*NC_ + n;
        const int rowbase = (b*S_ + n*CK_)*H_ + h;

        // store state entering chunk n (pre-update) for phase 3
        {
            float4 s0 = *(float4*)&stT[srow][scol];
            float4 s1 = *(float4*)&stT[srow][scol+4];
            ushort4 p0, p1;
            p0.x=f2bf(s0.x); p0.y=f2bf(s0.y); p0.z=f2bf(s0.z); p0.w=f2bf(s0.w);
            p1.x=f2bf(s1.x); p1.y=f2bf(s1.y); p1.z=f2bf(s1.z); p1.w=f2bf(s1.w);
            size_t base = ((size_t)cid*128 + v0 + srow)*128 + scol;
            *(ushort4*)(STw + base)     = p0;
            *(ushort4*)(STw + base + 4) = p1;
        }
        const float a_dec = EGw[cid];
        // load kcd (bf16->fp32) and kd = K*RK'
        {
            const uint2* kcp = (const uint2*)(KCDw + (size_t)cid*8192);
            #pragma unroll
            for (int i = 0; i < 8; ++i) {
                int idx4 = tid + 256*i;
                int r = idx4 >> 5, c0 = (idx4 & 31)*4;
                uint2 pv = kcp[idx4];
                float4 f;
                f.x = bf2f((unsigned short)(pv.x & 0xffff));
                f.y = bf2f((unsigned short)(pv.x >> 16));
                f.z = bf2f((unsigned short)(pv.y & 0xffff));
                f.w = bf2f((unsigned short)(pv.y >> 16));
                *(float4*)&kc[r][c0] = f;
                float rk = RKw[cid*64 + r];
                float4 kv = *(const float4*)(K + (size_t)(rowbase + r*H_)*DK_ + c0);
                kv.x *= rk; kv.y *= rk; kv.z *= rk; kv.w *= rk;
                *(float4*)&kd[r][c0] = kv;
            }
        }
        // u accumulator init (2x2 tile)
        float u00,u01,u10,u11;
        {
            const unsigned short* up = Uw + (size_t)cid*8192;
            unsigned uv0 = *(const unsigned*)(up + r0*128 + v0 + w0v);
            unsigned uv1 = *(const unsigned*)(up + (r0+1)*128 + v0 + w0v);
            u00 = bf2f((unsigned short)(uv0 & 0xffff)); u01 = bf2f((unsigned short)(uv0 >> 16));
            u10 = bf2f((unsigned short)(uv1 & 0xffff)); u11 = bf2f((unsigned short)(uv1 >> 16));
        }
        __syncthreads();

        // vn = u - kc @ stT^T
        {
            float s00=u00, s01=u01, s10=u10, s11=u11;
            for (int k0 = 0; k0 < 128; k0 += 4) {
                float4 a0 = *(float4*)&kc[r0][k0];
                float4 a1 = *(float4*)&kc[r0+1][k0];
                float4 b0 = *(float4*)&stT[w0v][k0];
                float4 b1 = *(float4*)&stT[w0v+1][k0];
                s00 -= DOT4(a0,b0); s01 -= DOT4(a0,b1);
                s10 -= DOT4(a1,b0); s11 -= DOT4(a1,b1);
            }
            vn[r0][w0v] = s00;   vn[r0][w0v+1] = s01;
            vn[r0+1][w0v] = s10; vn[r0+1][w0v+1] = s11;
        }
        __syncthreads();

        // stT = a*stT + vn^T @ kd   (2w x 4k tile, in place)
        {
            float4 acc0 = *(float4*)&stT[w0s][k0s];
            float4 acc1 = *(float4*)&stT[w0s+1][k0s];
            acc0.x*=a_dec; acc0.y*=a_dec; acc0.z*=a_dec; acc0.w*=a_dec;
            acc1.x*=a_dec; acc1.y*=a_dec; acc1.z*=a_dec; acc1.w*=a_dec;
            for (int r = 0; r < 64; ++r) {
                float2 vv = *(float2*)&vn[r][w0s];
                float4 kv = *(float4*)&kd[r][k0s];
                acc0.x += vv.x*kv.x; acc0.y += vv.x*kv.y; acc0.z += vv.x*kv.z; acc0.w += vv.x*kv.w;
                acc1.x += vv.y*kv.x; acc1.y += vv.y*kv.y; acc1.z += vv.y*kv.z; acc1.w += vv.y*kv.w;
            }
            *(float4*)&stT[w0s][k0s]   = acc0;
            *(float4*)&stT[w0s+1][k0s] = acc1;
        }
        __syncthreads();
    }
}

// ---------------- Phase 3: outputs, fully parallel (4096 blocks = chunk x Dv-half) ----------------
__global__ __launch_bounds__(256) void dr_phase3(
    const float* __restrict__ Q,
    const unsigned short* __restrict__ Uw, const unsigned short* __restrict__ KCDw,
    const unsigned short* __restrict__ ATTNw, const unsigned short* __restrict__ STw,
    const float* __restrict__ RQw, float* __restrict__ Out)
{
    __shared__ float qg[64][132];    // q_norm*scale*exp(gcs)
    __shared__ float kc[64][132];    // kcd
    __shared__ float STl[64][132];   // state^T rows for this v-half: STl[v][k]
    __shared__ float at[64][68];     // attn (masked)
    __shared__ float vnT[64][68];    // v_new^T: vnT[v][r]

    const int tid = threadIdx.x;
    const int half = blockIdx.x & 1;
    const int cid = blockIdx.x >> 1;
    const int n = cid & (NC_-1), bh = cid >> 6;
    const int h = bh & (H_-1), b = bh >> 4;
    const int rowbase = (b*S_ + n*CK_)*H_ + h;
    const int vbase = half*64;

    #pragma unroll
    for (int i = 0; i < 8; ++i) {
        int idx4 = tid + 256*i;
        int r = idx4 >> 5, c0 = (idx4 & 31)*4;
        float rq = RQw[cid*64 + r];
        float4 qv = *(const float4*)(Q + (size_t)(rowbase + r*H_)*DK_ + c0);
        qv.x *= rq; qv.y *= rq; qv.z *= rq; qv.w *= rq;
        *(float4*)&qg[r][c0] = qv;
        uint2 kcv = ((const uint2*)(KCDw + (size_t)cid*8192))[idx4];
        float4 f;
        f.x = bf2f((unsigned short)(kcv.x & 0xffff));
        f.y = bf2f((unsigned short)(kcv.x >> 16));
        f.z = bf2f((unsigned short)(kcv.y & 0xffff));
        f.w = bf2f((unsigned short)(kcv.y >> 16));
        *(float4*)&kc[r][c0] = f;
        uint2 stv = ((const uint2*)(STw + ((size_t)cid*128 + vbase)*128))[idx4];
        float4 g;
        g.x = bf2f((unsigned short)(stv.x & 0xffff));
        g.y = bf2f((unsigned short)(stv.x >> 16));
        g.z = bf2f((unsigned short)(stv.y & 0xffff));
        g.w = bf2f((unsigned short)(stv.y >> 16));
        *(float4*)&STl[r][c0] = g;
    }
    #pragma unroll
    for (int i = 0; i < 4; ++i) {
        int idx4 = tid + 256*i;
        int r = idx4 >> 4, j0 = (idx4 & 15)*4;
        uint2 av = ((const uint2*)(ATTNw + (size_t)cid*4096))[idx4];
        at[r][j0]   = bf2f((unsigned short)(av.x & 0xffff));
        at[r][j0+1] = bf2f((unsigned short)(av.x >> 16));
        at[r][j0+2] = bf2f((unsigned short)(av.y & 0xffff));
        at[r][j0+3] = bf2f((unsigned short)(av.y >> 16));
    }
    __syncthreads();

    const int r0 = (tid & 15)*4, v4 = (tid >> 4)*4;

    // vn = u - kc @ state  (computed transposed: vnT[v][r])
    {
        float4 acc[4];   // acc[x] components = v offsets 0..3, row r0+x
        #pragma unroll
        for (int x = 0; x < 4; ++x) {
            ushort4 uv = *(const ushort4*)(Uw + (size_t)cid*8192 + (r0+x)*128 + vbase + v4);
            acc[x].x = bf2f(uv.x); acc[x].y = bf2f(uv.y); acc[x].z = bf2f(uv.z); acc[x].w = bf2f(uv.w);
        }
        for (int k0 = 0; k0 < 128; k0 += 4) {
            float4 ar[4], bv[4];
            #pragma unroll
            for (int x = 0; x < 4; ++x) ar[x] = *(float4*)&kc[r0+x][k0];
            #pragma unroll
            for (int y = 0; y < 4; ++y) bv[y] = *(float4*)&STl[v4+y][k0];
            #pragma unroll
            for (int x = 0; x < 4; ++x) {
                acc[x].x -= DOT4(ar[x], bv[0]);
                acc[x].y -= DOT4(ar[x], bv[1]);
                acc[x].z -= DOT4(ar[x], bv[2]);
                acc[x].w -= DOT4(ar[x], bv[3]);
            }
        }
        #pragma unroll
        for (int x = 0; x < 4; ++x) {
            vnT[v4][r0+x]   = acc[x].x;
            vnT[v4+1][r0+x] = acc[x].y;
            vnT[v4+2][r0+x] = acc[x].z;
            vnT[v4+3][r0+x] = acc[x].w;
        }
    }
    __syncthreads();

    // o = qg @ state + attn @ vn
    {
        float4 acc[4] = {};
        for (int k0 = 0; k0 < 128; k0 += 4) {
            float4 ar[4], bv[4];
            #pragma unroll
            for (int x = 0; x < 4; ++x) ar[x] = *(float4*)&qg[r0+x][k0];
            #pragma unroll
            for (int y = 0; y < 4; ++y) bv[y] = *(float4*)&STl[v4+y][k0];
            #pragma unroll
            for (int x = 0; x < 4; ++x) {
                acc[x].x += DOT4(ar[x], bv[0]);
                acc[x].y += DOT4(ar[x], bv[1]);
                acc[x].z += DOT4(ar[x], bv[2]);
                acc[x].w += DOT4(ar[x], bv[3]);
            }
        }
        for (int j0 = 0; j0 < 64; j0 += 4) {
            float4 ar[4], bv[4];
            #pragma unroll
            for (int x = 0; x < 4; ++x) ar[x] = *(float4*)&at[r0+x][j0];
            #pragma unroll
            for (int y = 0; y < 4; ++y) bv[y] = *(float4*)&vnT[v4+y][j0];
            #pragma unroll
            for (int x = 0; x < 4; ++x) {
                acc[x].x += DOT4(ar[x], bv[0]);
                acc[x].y += DOT4(ar[x], bv[1]);
                acc[x].z += DOT4(ar[x], bv[2]);
                acc[x].w += DOT4(ar[x], bv[3]);
            }
        }
        #pragma unroll
        for (int x = 0; x < 4; ++x)
            *(float4*)(Out + (size_t)(rowbase + (r0+x)*H_)*DV_ + vbase + v4) = acc[x];
    }
}

extern "C" void kernel_launch(void* const* d_in, const int* in_sizes, int n_in,
                              void* d_out, int out_size, void* d_ws, size_t ws_size,
                              hipStream_t stream) {
    (void)in_sizes; (void)n_in; (void)out_size; (void)ws_size;
    const float* Q  = (const float*)d_in[0];
    const float* K  = (const float*)d_in[1];
    const float* V  = (const float*)d_in[2];
    const float* G  = (const float*)d_in[3];
    const float* Bt = (const float*)d_in[4];
    float* Out = (float*)d_out;

    // ws layout: U bf16 | KCD bf16 | ATTN bf16 | ST bf16 | RQ f32 | RK f32 | EG f32  = ~152 MB
    unsigned short* Uw    = (unsigned short*)d_ws;
    unsigned short* KCDw  = Uw    + (size_t)2048*64*128;
    unsigned short* ATTNw = KCDw  + (size_t)2048*64*128;
    unsigned short* STw   = ATTNw + (size_t)2048*64*64;
    float* RQw = (float*)(STw + (size_t)2048*128*128);
    float* RKw = RQw + 2048*64;
    float* EGw = RKw + 2048*64;

    dr_phase1<<<2048, 256, 0, stream>>>(Q, K, V, G, Bt, Uw, KCDw, ATTNw, RQw, RKw, EGw);
    dr_phase2<<<256, 256, 0, stream>>>(K, Uw, KCDw, RKw, EGw, STw);
    dr_phase3<<<4096, 256, 0, stream>>>(Q, Uw, KCDw, ATTNw, STw, RQw, Out);
}